// Round 12
// baseline (329.154 us; speedup 1.0000x reference)
//
#include <hip/hip_runtime.h>
#include <cstddef>

// Problem constants (b=4, ch=128, h=w=64)
#define B_      4
#define C_      128
#define L_      4096      // h*w
#define DIN     256       // expand*ch
#define NH      4         // heads
#define HD      64        // head dim
#define DS      64        // d_state
#define CONVCH  384       // din + 2*ds
#define DPROJ   644       // 2*din + 2*ds + nh
#define CHUNK   32
#define NCHUNK  128       // L_/CHUNK

typedef short bf16x8 __attribute__((ext_vector_type(8)));
typedef float floatx16 __attribute__((ext_vector_type(16)));

__device__ __forceinline__ float siluf(float v) { return v / (1.f + __expf(-v)); }

__device__ __forceinline__ ushort f2bf(float v) {
  unsigned u = __float_as_uint(v);
  unsigned r = (u + 0x7fff + ((u >> 16) & 1)) >> 16;
  return (ushort)r;
}
__device__ __forceinline__ float bf2f(ushort h) {
  return __uint_as_float((unsigned)h << 16);
}

// ---------------------------------------------------------------------------
// K1: LayerNorm over channels; writes hi+lo bf16 A-fragments for in_proj MFMA.
__global__ __launch_bounds__(256) void ln_kernel(
    const float* __restrict__ noisy, const float* __restrict__ gamma,
    const float* __restrict__ beta, ushort* __restrict__ Ah,
    ushort* __restrict__ Al) {
  int row = blockIdx.x, b = blockIdx.y;
  int t = threadIdx.x;
  int px = t & 63, cg = t >> 6;
  __shared__ float tile[64 * 129];
  __shared__ float ps[4][64], pq[4][64];
  __shared__ float smu[64], srs[64];
  float s = 0.f, s2 = 0.f;
  const float* src = noisy + ((size_t)b * C_) * L_ + row * 64;
  for (int i = 0; i < 32; ++i) {
    int c = cg * 32 + i;
    float v = src[(size_t)c * L_ + px];
    tile[px * 129 + c] = v;
    s += v; s2 += v * v;
  }
  ps[cg][px] = s; pq[cg][px] = s2;
  __syncthreads();
  if (t < 64) {
    float a = ps[0][t] + ps[1][t] + ps[2][t] + ps[3][t];
    float q = pq[0][t] + pq[1][t] + pq[2][t] + pq[3][t];
    float mu = a * (1.f / 128.f);
    float var = q * (1.f / 128.f) - mu * mu;
    smu[t] = mu;
    srs[t] = rsqrtf(var + 1e-5f);
  }
  __syncthreads();
  int pg = (b * L_ + row * 64) >> 5;  // base pixel block
  for (int idx = t; idx < 4096; idx += 256) {
    int p2 = idx >> 6;       // pixel within row-tile
    int c0 = (idx & 63) * 2; // channel pair
    float v0 = (tile[p2 * 129 + c0] - smu[p2]) * srs[p2] * gamma[c0] + beta[c0];
    float v1 = (tile[p2 * 129 + c0 + 1] - smu[p2]) * srs[p2] * gamma[c0 + 1] + beta[c0 + 1];
    int kk = c0 >> 4;
    int l = (p2 & 31) + 32 * ((c0 & 15) >> 3);
    int j = c0 & 7;  // even
    size_t off = (((size_t)(pg + (p2 >> 5))) * 8 + kk) * 512 + l * 8 + j;
    ushort h0 = f2bf(v0), h1 = f2bf(v1);
    float r0 = v0 - bf2f(h0), r1 = v1 - bf2f(h1);
    *(unsigned*)(Ah + off) = (unsigned)h0 | ((unsigned)h1 << 16);
    *(unsigned*)(Al + off) = (unsigned)f2bf(r0) | ((unsigned)f2bf(r1) << 16);
  }
}

// ---------------------------------------------------------------------------
// wprep_all: fused weight prep — ipw (blocks 0..175), opw (176..303),
// fw1 (304..431), fw2 (432..559). All target regions are disjoint.
__global__ __launch_bounds__(256) void wprep_all(
    const float* __restrict__ ipw, ushort* __restrict__ Bh, ushort* __restrict__ Bl,
    const float* __restrict__ opw, ushort* __restrict__ Oh, ushort* __restrict__ Ol,
    const float* __restrict__ fw1, ushort* __restrict__ Wt1,
    const float* __restrict__ fw2, ushort* __restrict__ Wt2) {
  int bi = blockIdx.x;
  int t = threadIdx.x;
  if (bi < 176) {
    int e = bi * 256 + t;
    int d = e >> 6;
    int c0 = (e & 63) * 2;
    int kk = c0 >> 4;
    int l = (d & 31) + 32 * ((c0 & 15) >> 3);
    int j = c0 & 7;
    size_t off = (((size_t)(d >> 5)) * 8 + kk) * 512 + l * 8 + j;
    float v0 = d < 644 ? ipw[(size_t)d * 128 + c0] : 0.f;
    float v1 = d < 644 ? ipw[(size_t)d * 128 + c0 + 1] : 0.f;
    ushort h0 = f2bf(v0), h1 = f2bf(v1);
    *(unsigned*)(Bh + off) = (unsigned)h0 | ((unsigned)h1 << 16);
    *(unsigned*)(Bl + off) = (unsigned)f2bf(v0 - bf2f(h0)) |
                             ((unsigned)f2bf(v1 - bf2f(h1)) << 16);
  } else if (bi < 304) {
    int e = (bi - 176) * 256 + t;  // 0..32767
    int d = e >> 8;
    int c = e & 255;
    size_t f = ((size_t)(d >> 5) * 16 + (c >> 4)) * 512 +
               ((d & 31) + 32 * ((c & 15) >> 3)) * 8 + (c & 7);
    float v = opw[(size_t)d * 256 + c];
    ushort h = f2bf(v);
    Oh[f] = h;
    Ol[f] = f2bf(v - bf2f(h));
  } else {
    const float* w = (bi < 432) ? fw1 : fw2;
    ushort* Wt = (bi < 432) ? Wt1 : Wt2;
    int co = (bi < 432) ? (bi - 304) : (bi - 432);  // 0..127
    int cb = co >> 5;
    for (int k = t; k < 1152; k += 256) {
      int kk = k >> 4, k16 = k & 15;
      int l = (co & 31) + 32 * (k16 >> 3);
      int off = (kk * 4 + cb) * 512 + l * 8 + (k16 & 7);
      Wt[off] = f2bf(w[(size_t)co * 1152 + k]);
    }
  }
}

// ---------------------------------------------------------------------------
// gemm1_mfma: in_proj, 3-term split-bf16, direct fragment loads (no LDS).
__global__ __launch_bounds__(256) void gemm1_mfma(
    const ushort* __restrict__ Ah, const ushort* __restrict__ Al,
    const ushort* __restrict__ Bh, const ushort* __restrict__ Bl,
    float* __restrict__ ZX) {
  int bn = blockIdx.x, bm = blockIdx.y;
  int t = threadIdx.x;
  int w = t >> 6, lane = t & 63;
  int pb = w >> 1, db = w & 1;
  size_t abase = ((size_t)(bm * 2 + pb) * 8) * 64 + lane;
  size_t bbase = ((size_t)(bn * 2 + db) * 8) * 64 + lane;
  const bf16x8* pAh = (const bf16x8*)Ah + abase;
  const bf16x8* pAl = (const bf16x8*)Al + abase;
  const bf16x8* pBh = (const bf16x8*)Bh + bbase;
  const bf16x8* pBl = (const bf16x8*)Bl + bbase;
  floatx16 acc;
#pragma unroll
  for (int i = 0; i < 16; ++i) acc[i] = 0.f;
#pragma unroll
  for (int kk = 0; kk < 8; ++kk) {
    bf16x8 ah = pAh[kk * 64], al = pAl[kk * 64];
    bf16x8 bh = pBh[kk * 64], bl = pBl[kk * 64];
    acc = __builtin_amdgcn_mfma_f32_32x32x16_bf16(ah, bh, acc, 0, 0, 0);
    acc = __builtin_amdgcn_mfma_f32_32x32x16_bf16(al, bh, acc, 0, 0, 0);
    acc = __builtin_amdgcn_mfma_f32_32x32x16_bf16(ah, bl, acc, 0, 0, 0);
  }
  int d = bn * 64 + db * 32 + (lane & 31);
  if (d < 644) {
    int rowadd = 4 * (lane >> 5);
#pragma unroll
    for (int r = 0; r < 16; ++r) {
      int rowm = (r & 3) + 8 * (r >> 2) + rowadd;
      int pix = bm * 64 + pb * 32 + rowm;
      ZX[(size_t)pix * DPROJ + d] = acc[r];
    }
  }
}

// ---------------------------------------------------------------------------
// K3: depthwise causal conv1d (k=5) + bias + silu; 16 outputs/thread.
__global__ __launch_bounds__(384) void conv1d_silu(
    const float* __restrict__ ZX, const float* __restrict__ cw,
    const float* __restrict__ cb, float* __restrict__ XBC) {
  int ch = threadIdx.x;
  int l0 = blockIdx.x * 16, b = blockIdx.y;
  const float* base = ZX + ((size_t)b * L_) * DPROJ + DIN + ch;
  float w0 = cw[ch * 5], w1 = cw[ch * 5 + 1], w2 = cw[ch * 5 + 2],
        w3 = cw[ch * 5 + 3], w4 = cw[ch * 5 + 4];
  float bias = cb[ch];
  float win[20];
#pragma unroll
  for (int i = 0; i < 20; ++i) {
    int ll = l0 - 4 + i;
    win[i] = ll >= 0 ? base[(size_t)ll * DPROJ] : 0.f;
  }
  float* dst = XBC + ((size_t)(b * L_ + l0)) * CONVCH + ch;
#pragma unroll
  for (int j = 0; j < 16; ++j) {
    float acc = bias + w0 * win[j] + w1 * win[j + 1] + w2 * win[j + 2] +
                w3 * win[j + 3] + w4 * win[j + 4];
    dst[(size_t)j * CONVCH] = siluf(acc);
  }
}

// ---------------------------------------------------------------------------
// K5: scan pass A v3 (CHUNK=32) — LDS-broadcast staging, single stage.
// grid (NCHUNK, NH, B_), block 256.
#define UPDA(k, B4, C4) \
  st[4*k+0] = st[4*k+0]*da + cf*B4.x; y0 += st[4*k+0]*C4.x; \
  st[4*k+1] = st[4*k+1]*da + cf*B4.y; y1 += st[4*k+1]*C4.y; \
  st[4*k+2] = st[4*k+2]*da + cf*B4.z; y2 += st[4*k+2]*C4.z; \
  st[4*k+3] = st[4*k+3]*da + cf*B4.w; y3 += st[4*k+3]*C4.w;

__global__ __launch_bounds__(256, 4) void scan_passA(
    const float* __restrict__ XBC, const float* __restrict__ ZX,
    const float* __restrict__ dt_bias, const float* __restrict__ A_log,
    float* __restrict__ YL, float* __restrict__ SC, float* __restrict__ PC,
    float* __restrict__ CUM) {
  int chunk = blockIdx.x, h = blockIdx.y, b = blockIdx.z;
  int t = threadIdx.x;
  int p = t >> 2, q = t & 3;
  int bh = b * NH + h;
  int l0 = chunk * CHUNK;
  __shared__ float sdt[CHUNK], sda[CHUNK];
  __shared__ float sB[32][64];
  __shared__ float sCc[32][64];
  __shared__ float sx[32][64];
  if (t < CHUNK) {
    float v = ZX[((size_t)(b * L_ + l0 + t)) * DPROJ + 640 + h] + dt_bias[h];
    float dt = v > 20.f ? v : log1pf(expf(v));
    sdt[t] = dt;
    sda[t] = expf(dt * -expf(A_log[h]));
  }
  size_t rowbase = ((size_t)(b * L_ + l0)) * CONVCH;
  float* __restrict__ yl = YL + ((size_t)(b * L_ + l0)) * DIN + h * HD + p;
  float* __restrict__ cumout = CUM + (size_t)bh * L_ + l0;
#pragma unroll
  for (int i = 0; i < 2; ++i) {
    int e = t + i * 256;                 // 0..511
    int row = e >> 4, c4 = (e & 15) * 4;
    const float* gsrc = XBC + rowbase + (size_t)row * CONVCH;
    *(float4*)&sB[row][c4]  = *(const float4*)(gsrc + DIN + c4);
    *(float4*)&sCc[row][c4] = *(const float4*)(gsrc + DIN + DS + c4);
    *(float4*)&sx[row][c4]  = *(const float4*)(gsrc + h * HD + c4);
  }
  __syncthreads();
  float st[16];
#pragma unroll
  for (int j = 0; j < 16; ++j) st[j] = 0.f;
  float cum = 1.f;
#pragma unroll 4
  for (int tl = 0; tl < CHUNK; ++tl) {
    float da = sda[tl], dtv = sdt[tl];
    float x = sx[tl][p];
    float cf = dtv * x;
    const float4* br = (const float4*)&sB[tl][q * 16];
    const float4* cr = (const float4*)&sCc[tl][q * 16];
    float4 B0 = br[0], B1 = br[1], B2 = br[2], B3 = br[3];
    float4 C0 = cr[0], C1 = cr[1], C2 = cr[2], C3 = cr[3];
    float y0 = 0.f, y1 = 0.f, y2 = 0.f, y3 = 0.f;
    UPDA(0, B0, C0) UPDA(1, B1, C1) UPDA(2, B2, C2) UPDA(3, B3, C3)
    float y = (y0 + y1) + (y2 + y3);
    y += __shfl_xor(y, 1);
    y += __shfl_xor(y, 2);
    cum *= da;
    if (q == 0) yl[(size_t)tl * DIN] = y;
    if (t == 0) cumout[tl] = cum;
  }
  float* scp = SC + ((size_t)bh * NCHUNK + chunk) * 4096 + p * 64 + q * 16;
  *(float4*)(scp + 0)  = make_float4(st[0], st[1], st[2], st[3]);
  *(float4*)(scp + 4)  = make_float4(st[4], st[5], st[6], st[7]);
  *(float4*)(scp + 8)  = make_float4(st[8], st[9], st[10], st[11]);
  *(float4*)(scp + 12) = make_float4(st[12], st[13], st[14], st[15]);
  if (t == 0) PC[bh * NCHUNK + chunk] = cum;
}

// ---------------------------------------------------------------------------
// K6: element-parallel in-place scan over chunks: SC[c] <- exclusive prefix state.
__global__ __launch_bounds__(256) void scan_passB(
    float* __restrict__ SC, const float* __restrict__ PC) {
  int bh = blockIdx.x >> 4;
  int eg = blockIdx.x & 15;
  int e = eg * 256 + threadIdx.x;
  float h = 0.f;
#pragma unroll 8
  for (int c = 0; c < NCHUNK; ++c) {
    size_t idx = ((size_t)bh * NCHUNK + c) * 4096 + e;
    float s = SC[idx];
    float pcv = PC[bh * NCHUNK + c];
    SC[idx] = h;
    h = h * pcv + s;
  }
}

// ---------------------------------------------------------------------------
// K7: pass C — LDS-broadcast staging (CHUNK=32: 2 tq groups of 16).
// grid (NCHUNK*2, NH, B_), block 256.
__global__ __launch_bounds__(256) void scan_passC(
    const float* __restrict__ XBC, const float* __restrict__ SC,
    const float* __restrict__ CUM, const float* __restrict__ Dp,
    float* __restrict__ YL) {
  int chunk = blockIdx.x >> 1, tq = blockIdx.x & 1;
  int h = blockIdx.y, b = blockIdx.z;
  int t = threadIdx.x;
  int p = t >> 2, q = t & 3;
  int bh = b * NH + h;
  __shared__ float sCc[16][64];
  __shared__ float sx[16][64];
  __shared__ float scum[16];
  int t0 = tq * 16;
  int l0 = chunk * CHUNK + t0;
  size_t rowbase = ((size_t)(b * L_ + l0)) * CONVCH;
  {
    int row = t >> 4, c4 = (t & 15) * 4;
    const float* gsrc = XBC + rowbase + (size_t)row * CONVCH;
    *(float4*)&sCc[row][c4] = *(const float4*)(gsrc + DIN + DS + c4);
    *(float4*)&sx[row][c4]  = *(const float4*)(gsrc + h * HD + c4);
    if (t < 16) scum[t] = CUM[(size_t)bh * L_ + l0 + t];
  }
  const float* hi = SC + ((size_t)bh * NCHUNK + chunk) * 4096 + p * 64 + q * 16;
  float hreg[16];
  {
    float4 v;
    v = *(const float4*)(hi + 0);  hreg[0] = v.x; hreg[1] = v.y; hreg[2] = v.z; hreg[3] = v.w;
    v = *(const float4*)(hi + 4);  hreg[4] = v.x; hreg[5] = v.y; hreg[6] = v.z; hreg[7] = v.w;
    v = *(const float4*)(hi + 8);  hreg[8] = v.x; hreg[9] = v.y; hreg[10] = v.z; hreg[11] = v.w;
    v = *(const float4*)(hi + 12); hreg[12] = v.x; hreg[13] = v.y; hreg[14] = v.z; hreg[15] = v.w;
  }
  float Dv = Dp[h];
  float* __restrict__ yl = YL + ((size_t)(b * L_ + l0)) * DIN + h * HD + p;
  __syncthreads();
#pragma unroll 4
  for (int tl = 0; tl < 16; ++tl) {
    const float4* cr = (const float4*)&sCc[tl][q * 16];
    float4 C0 = cr[0], C1 = cr[1], C2 = cr[2], C3 = cr[3];
    float x = sx[tl][p];
    float cum = scum[tl];
    float y0 = 0.f, y1 = 0.f, y2 = 0.f, y3 = 0.f;
    y0 += hreg[0]*C0.x;  y1 += hreg[1]*C0.y;  y2 += hreg[2]*C0.z;  y3 += hreg[3]*C0.w;
    y0 += hreg[4]*C1.x;  y1 += hreg[5]*C1.y;  y2 += hreg[6]*C1.z;  y3 += hreg[7]*C1.w;
    y0 += hreg[8]*C2.x;  y1 += hreg[9]*C2.y;  y2 += hreg[10]*C2.z; y3 += hreg[11]*C2.w;
    y0 += hreg[12]*C3.x; y1 += hreg[13]*C3.y; y2 += hreg[14]*C3.z; y3 += hreg[15]*C3.w;
    float y = (y0 + y1) + (y2 + y3);
    y += __shfl_xor(y, 1);
    y += __shfl_xor(y, 2);
    if (q == 0) {
      size_t o = (size_t)tl * DIN;
      yl[o] = yl[o] + cum * y + x * Dv;
    }
  }
}

// ---------------------------------------------------------------------------
// gate_gemm (R8 version): fused gating + RMSNorm + out_proj GEMM -> MBUF.
// grid (256), block 256; 64 pixels/block.
__global__ __launch_bounds__(256) void gate_gemm(
    const float* __restrict__ YL, const float* __restrict__ ZX,
    const float* __restrict__ rmsw,
    const ushort* __restrict__ Oh, const ushort* __restrict__ Ol,
    float* __restrict__ MBUF) {
  __shared__ ushort AhL[16384];   // 32 KB
  __shared__ ushort AlL[16384];   // 32 KB
  int t = threadIdx.x;
  int lp = t & 31, pp = t >> 5;
  int pix0 = blockIdx.x * 64;
  float4 w0 = *(const float4*)(rmsw + lp * 4);
  float4 w1 = *(const float4*)(rmsw + 128 + lp * 4);
  for (int it = 0; it < 8; ++it) {
    int pl = it * 8 + pp;
    size_t pix = (size_t)pix0 + pl;
    const float* y = YL + pix * DIN;
    const float* z = ZX + pix * DPROJ;
    float4 y0 = *(const float4*)(y + lp * 4);
    float4 y1 = *(const float4*)(y + 128 + lp * 4);
    float4 z0 = *(const float4*)(z + lp * 4);
    float4 z1 = *(const float4*)(z + 128 + lp * 4);
    float g[8];
    g[0] = y0.x * siluf(z0.x); g[1] = y0.y * siluf(z0.y);
    g[2] = y0.z * siluf(z0.z); g[3] = y0.w * siluf(z0.w);
    g[4] = y1.x * siluf(z1.x); g[5] = y1.y * siluf(z1.y);
    g[6] = y1.z * siluf(z1.z); g[7] = y1.w * siluf(z1.w);
    float ss = 0.f;
#pragma unroll
    for (int j = 0; j < 8; ++j) ss += g[j] * g[j];
    ss += __shfl_xor(ss, 16);
    ss += __shfl_xor(ss, 8);
    ss += __shfl_xor(ss, 4);
    ss += __shfl_xor(ss, 2);
    ss += __shfl_xor(ss, 1);
    float rs = rsqrtf(ss * (1.f / 256.f) + 1e-5f);
    float o[8];
    o[0] = g[0] * rs * w0.x; o[1] = g[1] * rs * w0.y;
    o[2] = g[2] * rs * w0.z; o[3] = g[3] * rs * w0.w;
    o[4] = g[4] * rs * w1.x; o[5] = g[5] * rs * w1.y;
    o[6] = g[6] * rs * w1.z; o[7] = g[7] * rs * w1.w;
#pragma unroll
    for (int grp = 0; grp < 2; ++grp) {
      int d = grp * 128 + lp * 4;
      int off = ((pl >> 5) * 16 + (d >> 4)) * 512 +
                ((pl & 31) + 32 * ((d & 15) >> 3)) * 8 + (d & 7);
      ushort h0 = f2bf(o[grp*4+0]), h1 = f2bf(o[grp*4+1]);
      ushort h2 = f2bf(o[grp*4+2]), h3 = f2bf(o[grp*4+3]);
      uint2 hv, lv;
      hv.x = (unsigned)h0 | ((unsigned)h1 << 16);
      hv.y = (unsigned)h2 | ((unsigned)h3 << 16);
      lv.x = (unsigned)f2bf(o[grp*4+0] - bf2f(h0)) | ((unsigned)f2bf(o[grp*4+1] - bf2f(h1)) << 16);
      lv.y = (unsigned)f2bf(o[grp*4+2] - bf2f(h2)) | ((unsigned)f2bf(o[grp*4+3] - bf2f(h3)) << 16);
      *(uint2*)(AhL + off) = hv;
      *(uint2*)(AlL + off) = lv;
    }
  }
  __syncthreads();
  int w = t >> 6, lane = t & 63;
  int pb = w >> 1, db = w & 1;
  const bf16x8* pBh = (const bf16x8*)Oh;
  const bf16x8* pBl = (const bf16x8*)Ol;
  int rowadd = 4 * (lane >> 5);
#pragma unroll
  for (int bn = 0; bn < 2; ++bn) {
    floatx16 acc;
#pragma unroll
    for (int i = 0; i < 16; ++i) acc[i] = 0.f;
    size_t bbase = ((size_t)(bn * 2 + db) * 16) * 64 + lane;
#pragma unroll
    for (int kk = 0; kk < 16; ++kk) {
      bf16x8 ah = *(const bf16x8*)(AhL + (pb * 16 + kk) * 512 + lane * 8);
      bf16x8 al = *(const bf16x8*)(AlL + (pb * 16 + kk) * 512 + lane * 8);
      bf16x8 bh = pBh[bbase + (size_t)kk * 64];
      bf16x8 bl = pBl[bbase + (size_t)kk * 64];
      acc = __builtin_amdgcn_mfma_f32_32x32x16_bf16(ah, bh, acc, 0, 0, 0);
      acc = __builtin_amdgcn_mfma_f32_32x32x16_bf16(al, bh, acc, 0, 0, 0);
      acc = __builtin_amdgcn_mfma_f32_32x32x16_bf16(ah, bl, acc, 0, 0, 0);
    }
    int c = bn * 64 + db * 32 + (lane & 31);
#pragma unroll
    for (int r = 0; r < 16; ++r) {
      int rowm = (r & 3) + 8 * (r >> 2) + rowadd;
      int pix = pix0 + pb * 32 + rowm;
      MBUF[(size_t)pix * C_ + c] = acc[r];
    }
  }
}

// ---------------------------------------------------------------------------
// K10: transpose (b,L,128) -> (b,128,L) and add noisy -> YRES.
__global__ __launch_bounds__(256) void transpose_add(
    const float* __restrict__ M, const float* __restrict__ noisy, float* __restrict__ YRES) {
  int row = blockIdx.x, b = blockIdx.y;
  int t = threadIdx.x;
  __shared__ float tile[64 * 129];
  const float* src = M + ((size_t)(b * L_ + row * 64)) * C_;
  for (int idx = t; idx < 8192; idx += 256) {
    int px = idx >> 7, c = idx & 127;
    tile[px * 129 + c] = src[idx];
  }
  __syncthreads();
  for (int idx = t; idx < 8192; idx += 256) {
    int c = idx >> 6, px = idx & 63;
    size_t o = ((size_t)(b * C_ + c)) * L_ + row * 64 + px;
    YRES[o] = noisy[o] + tile[px * 129 + c];
  }
}

// ---------------------------------------------------------------------------
// im2col: coalesced 16B fragment writes. grid (36 kk-pairs, 64 y, 4 b), block 256.
template <typename T>
__global__ __launch_bounds__(256) void im2col_kernel(
    const T* __restrict__ src, ushort* __restrict__ Bm) {
  int y = blockIdx.y, b = blockIdx.z;
  int t = threadIdx.x;
  int kk = blockIdx.x * 2 + (t >> 7);
  int r = t & 127;
  int nb = r >> 6, l = r & 63;
  int x = nb * 32 + (l & 31);
  int ki0 = (l >> 5) * 8;
  const T* sb = src + (size_t)b * C_ * L_;
  ushort vals[8];
#pragma unroll
  for (int j = 0; j < 8; ++j) {
    int k = kk * 16 + ki0 + j;
    int ci = k / 9, rr = k - ci * 9;
    int iy = rr / 3, ix = rr - iy * 3;
    int yy = y + iy - 1; yy = yy < 0 ? -yy : (yy > 63 ? 126 - yy : yy);
    int xx = x + ix - 1; xx = xx < 0 ? -xx : (xx > 63 ? 126 - xx : xx);
    T v = sb[(size_t)ci * L_ + yy * 64 + xx];
    if constexpr (sizeof(T) == 4) vals[j] = f2bf((float)v);
    else vals[j] = (ushort)v;
  }
  ushort* dst = Bm + (((size_t)(b * 64 + y)) * 72 + kk) * 1024 + nb * 512 + l * 8;
  *(int4*)dst = *(int4*)vals;
}

// ---------------------------------------------------------------------------
// conv_mfma: direct fragment loads. MODE 0: bf16 out. MODE 1: fp32
// out = res + relu(conv), plus fused aux passthrough. grid (2, 64, 4), block 256.
template <int MODE>
__global__ __launch_bounds__(256) void conv_mfma(
    const ushort* __restrict__ Wt, const ushort* __restrict__ Bm,
    const float* __restrict__ bias, const float* __restrict__ res,
    void* __restrict__ outv, const float* __restrict__ aux) {
  int cog = blockIdx.x, y = blockIdx.y, b = blockIdx.z;
  int t = threadIdx.x;
  int w = t >> 6, lane = t & 63;
  int cb = w >> 1, nb = w & 1;
  const bf16x8* pW = (const bf16x8*)Wt + (size_t)(cog * 2 + cb) * 64 + lane;
  const bf16x8* pB = (const bf16x8*)Bm + ((size_t)(b * 64 + y) * 72) * 128 +
                     (size_t)nb * 64 + lane;
  floatx16 acc;
#pragma unroll
  for (int i = 0; i < 16; ++i) acc[i] = 0.f;
#pragma unroll 8
  for (int kk = 0; kk < 72; ++kk) {
    bf16x8 af = pW[(size_t)kk * 256];
    bf16x8 bf = pB[(size_t)kk * 128];
    acc = __builtin_amdgcn_mfma_f32_32x32x16_bf16(af, bf, acc, 0, 0, 0);
  }
  int x0 = nb * 32 + (lane & 31);
  int rowadd = 4 * (lane >> 5);
#pragma unroll
  for (int r = 0; r < 16; ++r) {
    int rowm = (r & 3) + 8 * (r >> 2) + rowadd;
    int co = cog * 64 + cb * 32 + rowm;
    size_t o = ((size_t)(b * C_ + co)) * L_ + y * 64 + x0;
    float v = fmaxf(acc[r] + bias[co], 0.f);
    if (MODE == 0) {
      ((ushort*)outv)[o] = f2bf(v);
    } else {
      ((float*)outv)[o] = v + res[o];
    }
  }
  if (MODE == 1) {
    // fused aux passthrough: 512 blocks x 256 threads x 16 floats = 2M
    int bid = blockIdx.x + 2 * (blockIdx.y + 64 * blockIdx.z);
    size_t base = ((size_t)bid * 256 + t) * 16;
    float* o2 = (float*)outv + 2097152;
#pragma unroll
    for (int i = 0; i < 4; ++i) {
      *(float4*)(o2 + base + i * 4) = *(const float4*)(aux + base + i * 4);
    }
  }
}

// ---------------------------------------------------------------------------
extern "C" void kernel_launch(void* const* d_in, const int* in_sizes, int n_in,
                              void* d_out, int out_size, void* d_ws, size_t ws_size,
                              hipStream_t stream) {
  const float* noisy   = (const float*)d_in[0];
  const float* aux     = (const float*)d_in[1];
  const float* ln_g    = (const float*)d_in[2];
  const float* ln_b    = (const float*)d_in[3];
  const float* ipw     = (const float*)d_in[4];
  const float* cw      = (const float*)d_in[5];
  const float* cbv     = (const float*)d_in[6];
  const float* A_log   = (const float*)d_in[7];
  const float* dt_bias = (const float*)d_in[8];
  const float* Dp      = (const float*)d_in[9];
  const float* rmsw    = (const float*)d_in[10];
  const float* opw     = (const float*)d_in[11];
  const float* fw1     = (const float*)d_in[12];
  const float* fb1     = (const float*)d_in[13];
  const float* fw2     = (const float*)d_in[14];
  const float* fb2     = (const float*)d_in[15];
  float* out = (float*)d_out;
  float* ws  = (float*)d_ws;

  // Workspace layout (floats). SC moved to its own region (CHUNK=32 doubles
  // its size to 8.4M floats). Total ~34M floats = 136 MB (< 256 MiB ws).
  const size_t OFF_ZX  = 0;                            // 16384*644; Bm aliases at conv time
  const size_t OFF_XBC = OFF_ZX + 16384UL * 644;       // 16384*384; MBUF aliases after passC
  const size_t OFF_SCN = OFF_XBC + 16384UL * 384;      // 4,194,304: Ah/Al -> FF1(bf16)|YRES
  const size_t OFF_WT  = OFF_SCN + 4194304UL;          // 73,728: Wt1
  const size_t OFF_WO  = OFF_WT + 73728UL;             // 32,768: Woh+Wol
  const size_t OFF_CUM = OFF_WT + 131072UL;            // 65,536: CUM
  const size_t OFF_YL  = OFF_CUM + 65536UL;            // 16384*256; Bn hi+lo alias (pre-scan)
  const size_t OFF_PC  = OFF_YL + 16384UL * 256;       // 2,048 (16 bh x 128 chunks)
  const size_t OFF_WT2 = OFF_PC + 2048UL;              // 73,728: Wt2
  const size_t OFF_SC  = OFF_WT2 + 73728UL;            // 8,388,608: SC (disjoint)

  float* ZX   = ws + OFF_ZX;
  float* XBC  = ws + OFF_XBC;
  float* SC   = ws + OFF_SC;
  float* CUM  = ws + OFF_CUM;
  float* YL   = ws + OFF_YL;
  float* PC   = ws + OFF_PC;
  ushort* Ah   = (ushort*)(ws + OFF_SCN);          // ln frags (dead before FF1/YRES)
  ushort* Al   = Ah + 16384UL * 128;
  ushort* Bnh  = (ushort*)(ws + OFF_YL);           // in_proj weight frags (dead before YL)
  ushort* Bnl  = Bnh + 45056UL * 2;
  ushort* Wt1 = (ushort*)(ws + OFF_WT);            // 147,456 ushorts
  ushort* Woh  = (ushort*)(ws + OFF_WO);           // out_proj weight frags
  ushort* Wol  = Woh + 32768UL;
  ushort* Wt2 = (ushort*)(ws + OFF_WT2);           // 147,456 ushorts
  float* MBUF = ws + OFF_XBC;                      // alias: XBC dead after passC
  ushort* FF1 = (ushort*)(ws + OFF_SCN);           // bf16, Ah/Al dead after gemm1
  float* YRES = ws + OFF_SCN + 2097152UL;          // last 2M floats of SCN
  ushort* Bm  = (ushort*)(ws + OFF_ZX);            // after gate_gemm (ZX dead)

  // 1) all weight preps (in_proj, out_proj, conv1, conv2)
  wprep_all<<<560, 256, 0, stream>>>(ipw, Bnh, Bnl, opw, Woh, Wol, fw1, Wt1, fw2, Wt2);
  // 2) LN -> hi+lo bf16 A-fragments
  ln_kernel<<<dim3(64, 4), 256, 0, stream>>>(noisy, ln_g, ln_b, Ah, Al);
  // 3) in_proj GEMM (split-bf16 MFMA) -> ZX
  gemm1_mfma<<<dim3(11, 256), 256, 0, stream>>>(Ah, Al, Bnh, Bnl, ZX);
  // 4) depthwise conv1d + silu -> XBC
  conv1d_silu<<<dim3(L_ / 16, B_), 384, 0, stream>>>(ZX, cw, cbv, XBC);
  // 5) chunked scan (CHUNK=32, v3 LDS-broadcast staging)
  scan_passA<<<dim3(NCHUNK, NH, B_), 256, 0, stream>>>(XBC, ZX, dt_bias, A_log, YL, SC, PC, CUM);
  scan_passB<<<256, 256, 0, stream>>>(SC, PC);
  scan_passC<<<dim3(NCHUNK * 2, NH, B_), 256, 0, stream>>>(XBC, SC, CUM, Dp, YL);
  // 6) fused gate + RMSNorm + out_proj GEMM -> MBUF (16384 x 128)
  gate_gemm<<<256, 256, 0, stream>>>(YL, ZX, rmsw, Woh, Wol, MBUF);
  // 7) transpose back + residual -> YRES (b,C,H,W)
  transpose_add<<<dim3(64, 4), 256, 0, stream>>>(MBUF, noisy, YRES);
  // 8) ff1 = relu(conv3x3(YRES)) via bf16 MFMA implicit GEMM (bf16 output)
  im2col_kernel<float><<<dim3(36, 64, 4), 256, 0, stream>>>(YRES, Bm);
  conv_mfma<0><<<dim3(2, 64, 4), 256, 0, stream>>>(Wt1, Bm, fb1, nullptr, FF1, nullptr);
  // 9) out_y = YRES + relu(conv3x3(FF1)); aux passthrough fused
  im2col_kernel<ushort><<<dim3(36, 64, 4), 256, 0, stream>>>(FF1, Bm);
  conv_mfma<1><<<dim3(2, 64, 4), 256, 0, stream>>>(Wt2, Bm, fb2, YRES, out, aux);
}

// Round 13
// 313.383 us; speedup vs baseline: 1.0503x; 1.0503x over previous
//
#include <hip/hip_runtime.h>
#include <cstddef>

// Problem constants (b=4, ch=128, h=w=64)
#define B_      4
#define C_      128
#define L_      4096      // h*w
#define DIN     256       // expand*ch
#define NH      4         // heads
#define HD      64        // head dim
#define DS      64        // d_state
#define CONVCH  384       // din + 2*ds
#define DPROJ   644       // 2*din + 2*ds + nh
#define CHUNK   64
#define NCHUNK  64        // L_/CHUNK

typedef short bf16x8 __attribute__((ext_vector_type(8)));
typedef float floatx16 __attribute__((ext_vector_type(16)));

__device__ __forceinline__ float siluf(float v) { return v / (1.f + __expf(-v)); }

__device__ __forceinline__ ushort f2bf(float v) {
  unsigned u = __float_as_uint(v);
  unsigned r = (u + 0x7fff + ((u >> 16) & 1)) >> 16;
  return (ushort)r;
}
__device__ __forceinline__ float bf2f(ushort h) {
  return __uint_as_float((unsigned)h << 16);
}

// ---------------------------------------------------------------------------
// K1: LayerNorm over channels; writes hi+lo bf16 A-fragments for in_proj MFMA.
__global__ __launch_bounds__(256) void ln_kernel(
    const float* __restrict__ noisy, const float* __restrict__ gamma,
    const float* __restrict__ beta, ushort* __restrict__ Ah,
    ushort* __restrict__ Al) {
  int row = blockIdx.x, b = blockIdx.y;
  int t = threadIdx.x;
  int px = t & 63, cg = t >> 6;
  __shared__ float tile[64 * 129];
  __shared__ float ps[4][64], pq[4][64];
  __shared__ float smu[64], srs[64];
  float s = 0.f, s2 = 0.f;
  const float* src = noisy + ((size_t)b * C_) * L_ + row * 64;
  for (int i = 0; i < 32; ++i) {
    int c = cg * 32 + i;
    float v = src[(size_t)c * L_ + px];
    tile[px * 129 + c] = v;
    s += v; s2 += v * v;
  }
  ps[cg][px] = s; pq[cg][px] = s2;
  __syncthreads();
  if (t < 64) {
    float a = ps[0][t] + ps[1][t] + ps[2][t] + ps[3][t];
    float q = pq[0][t] + pq[1][t] + pq[2][t] + pq[3][t];
    float mu = a * (1.f / 128.f);
    float var = q * (1.f / 128.f) - mu * mu;
    smu[t] = mu;
    srs[t] = rsqrtf(var + 1e-5f);
  }
  __syncthreads();
  int pg = (b * L_ + row * 64) >> 5;  // base pixel block
  for (int idx = t; idx < 4096; idx += 256) {
    int p2 = idx >> 6;       // pixel within row-tile
    int c0 = (idx & 63) * 2; // channel pair
    float v0 = (tile[p2 * 129 + c0] - smu[p2]) * srs[p2] * gamma[c0] + beta[c0];
    float v1 = (tile[p2 * 129 + c0 + 1] - smu[p2]) * srs[p2] * gamma[c0 + 1] + beta[c0 + 1];
    int kk = c0 >> 4;
    int l = (p2 & 31) + 32 * ((c0 & 15) >> 3);
    int j = c0 & 7;  // even
    size_t off = (((size_t)(pg + (p2 >> 5))) * 8 + kk) * 512 + l * 8 + j;
    ushort h0 = f2bf(v0), h1 = f2bf(v1);
    float r0 = v0 - bf2f(h0), r1 = v1 - bf2f(h1);
    *(unsigned*)(Ah + off) = (unsigned)h0 | ((unsigned)h1 << 16);
    *(unsigned*)(Al + off) = (unsigned)f2bf(r0) | ((unsigned)f2bf(r1) << 16);
  }
}

// ---------------------------------------------------------------------------
// wprep_all: fused weight prep — ipw (blocks 0..175), opw (176..303),
// fw1 conv weights (304..431). Regions are disjoint (Wt1 has its full
// 73728-float extent; Woh/Wol placed past it).
__global__ __launch_bounds__(256) void wprep_all(
    const float* __restrict__ ipw, ushort* __restrict__ Bh, ushort* __restrict__ Bl,
    const float* __restrict__ opw, ushort* __restrict__ Oh, ushort* __restrict__ Ol,
    const float* __restrict__ fw1, ushort* __restrict__ Wt1) {
  int bi = blockIdx.x;
  int t = threadIdx.x;
  if (bi < 176) {
    int e = bi * 256 + t;
    int d = e >> 6;
    int c0 = (e & 63) * 2;
    int kk = c0 >> 4;
    int l = (d & 31) + 32 * ((c0 & 15) >> 3);
    int j = c0 & 7;
    size_t off = (((size_t)(d >> 5)) * 8 + kk) * 512 + l * 8 + j;
    float v0 = d < 644 ? ipw[(size_t)d * 128 + c0] : 0.f;
    float v1 = d < 644 ? ipw[(size_t)d * 128 + c0 + 1] : 0.f;
    ushort h0 = f2bf(v0), h1 = f2bf(v1);
    *(unsigned*)(Bh + off) = (unsigned)h0 | ((unsigned)h1 << 16);
    *(unsigned*)(Bl + off) = (unsigned)f2bf(v0 - bf2f(h0)) |
                             ((unsigned)f2bf(v1 - bf2f(h1)) << 16);
  } else if (bi < 304) {
    int e = (bi - 176) * 256 + t;  // 0..32767
    int d = e >> 8;
    int c = e & 255;
    size_t f = ((size_t)(d >> 5) * 16 + (c >> 4)) * 512 +
               ((d & 31) + 32 * ((c & 15) >> 3)) * 8 + (c & 7);
    float v = opw[(size_t)d * 256 + c];
    ushort h = f2bf(v);
    Oh[f] = h;
    Ol[f] = f2bf(v - bf2f(h));
  } else {
    int co = bi - 304;  // 0..127
    int cb = co >> 5;
    for (int k = t; k < 1152; k += 256) {
      int kk = k >> 4, k16 = k & 15;
      int l = (co & 31) + 32 * (k16 >> 3);
      int off = (kk * 4 + cb) * 512 + l * 8 + (k16 & 7);
      Wt1[off] = f2bf(fw1[(size_t)co * 1152 + k]);
    }
  }
}

// ---------------------------------------------------------------------------
// gemm1_mfma: in_proj, 3-term split-bf16, direct fragment loads (no LDS).
__global__ __launch_bounds__(256) void gemm1_mfma(
    const ushort* __restrict__ Ah, const ushort* __restrict__ Al,
    const ushort* __restrict__ Bh, const ushort* __restrict__ Bl,
    float* __restrict__ ZX) {
  int bn = blockIdx.x, bm = blockIdx.y;
  int t = threadIdx.x;
  int w = t >> 6, lane = t & 63;
  int pb = w >> 1, db = w & 1;
  size_t abase = ((size_t)(bm * 2 + pb) * 8) * 64 + lane;
  size_t bbase = ((size_t)(bn * 2 + db) * 8) * 64 + lane;
  const bf16x8* pAh = (const bf16x8*)Ah + abase;
  const bf16x8* pAl = (const bf16x8*)Al + abase;
  const bf16x8* pBh = (const bf16x8*)Bh + bbase;
  const bf16x8* pBl = (const bf16x8*)Bl + bbase;
  floatx16 acc;
#pragma unroll
  for (int i = 0; i < 16; ++i) acc[i] = 0.f;
#pragma unroll
  for (int kk = 0; kk < 8; ++kk) {
    bf16x8 ah = pAh[kk * 64], al = pAl[kk * 64];
    bf16x8 bh = pBh[kk * 64], bl = pBl[kk * 64];
    acc = __builtin_amdgcn_mfma_f32_32x32x16_bf16(ah, bh, acc, 0, 0, 0);
    acc = __builtin_amdgcn_mfma_f32_32x32x16_bf16(al, bh, acc, 0, 0, 0);
    acc = __builtin_amdgcn_mfma_f32_32x32x16_bf16(ah, bl, acc, 0, 0, 0);
  }
  int d = bn * 64 + db * 32 + (lane & 31);
  if (d < 644) {
    int rowadd = 4 * (lane >> 5);
#pragma unroll
    for (int r = 0; r < 16; ++r) {
      int rowm = (r & 3) + 8 * (r >> 2) + rowadd;
      int pix = bm * 64 + pb * 32 + rowm;
      ZX[(size_t)pix * DPROJ + d] = acc[r];
    }
  }
}

// ---------------------------------------------------------------------------
// K3: depthwise causal conv1d (k=5) + bias + silu; 16 outputs/thread.
__global__ __launch_bounds__(384) void conv1d_silu(
    const float* __restrict__ ZX, const float* __restrict__ cw,
    const float* __restrict__ cb, float* __restrict__ XBC) {
  int ch = threadIdx.x;
  int l0 = blockIdx.x * 16, b = blockIdx.y;
  const float* base = ZX + ((size_t)b * L_) * DPROJ + DIN + ch;
  float w0 = cw[ch * 5], w1 = cw[ch * 5 + 1], w2 = cw[ch * 5 + 2],
        w3 = cw[ch * 5 + 3], w4 = cw[ch * 5 + 4];
  float bias = cb[ch];
  float win[20];
#pragma unroll
  for (int i = 0; i < 20; ++i) {
    int ll = l0 - 4 + i;
    win[i] = ll >= 0 ? base[(size_t)ll * DPROJ] : 0.f;
  }
  float* dst = XBC + ((size_t)(b * L_ + l0)) * CONVCH + ch;
#pragma unroll
  for (int j = 0; j < 16; ++j) {
    float acc = bias + w0 * win[j] + w1 * win[j + 1] + w2 * win[j + 2] +
                w3 * win[j + 3] + w4 * win[j + 4];
    dst[(size_t)j * CONVCH] = siluf(acc);
  }
}

// ---------------------------------------------------------------------------
// K5: scan pass A — LDS-broadcast staging. grid (NCHUNK, NH, B_), block 256.
#define UPDA(k, B4, C4) \
  st[4*k+0] = st[4*k+0]*da + cf*B4.x; y0 += st[4*k+0]*C4.x; \
  st[4*k+1] = st[4*k+1]*da + cf*B4.y; y1 += st[4*k+1]*C4.y; \
  st[4*k+2] = st[4*k+2]*da + cf*B4.z; y2 += st[4*k+2]*C4.z; \
  st[4*k+3] = st[4*k+3]*da + cf*B4.w; y3 += st[4*k+3]*C4.w;

__global__ __launch_bounds__(256, 4) void scan_passA(
    const float* __restrict__ XBC, const float* __restrict__ ZX,
    const float* __restrict__ dt_bias, const float* __restrict__ A_log,
    float* __restrict__ YL, float* __restrict__ SC, float* __restrict__ PC,
    float* __restrict__ CUM) {
  int chunk = blockIdx.x, h = blockIdx.y, b = blockIdx.z;
  int t = threadIdx.x;
  int p = t >> 2, q = t & 3;
  int bh = b * NH + h;
  __shared__ float sdt[CHUNK], sda[CHUNK];
  __shared__ float sB[32][64];
  __shared__ float sCc[32][64];
  __shared__ float sx[32][64];
  if (t < CHUNK) {
    int l = chunk * CHUNK + t;
    float v = ZX[((size_t)(b * L_ + l)) * DPROJ + 640 + h] + dt_bias[h];
    float dt = v > 20.f ? v : log1pf(expf(v));
    sdt[t] = dt;
    sda[t] = expf(dt * -expf(A_log[h]));
  }
  size_t rowbase = ((size_t)b * L_ + (size_t)chunk * CHUNK) * CONVCH;
  float* __restrict__ yl = YL + ((size_t)b * L_ + (size_t)chunk * CHUNK) * DIN + h * HD + p;
  float* __restrict__ cumout = CUM + (size_t)bh * L_ + chunk * CHUNK;
  float st[16];
#pragma unroll
  for (int j = 0; j < 16; ++j) st[j] = 0.f;
  float cum = 1.f;
  for (int half = 0; half < 2; ++half) {
    __syncthreads();   // protects sdt (half 0) / prior-half LDS (half 1)
#pragma unroll
    for (int i = 0; i < 2; ++i) {
      int e = t + i * 256;                 // 0..511
      int row = e >> 4, c4 = (e & 15) * 4;
      const float* gsrc = XBC + rowbase + (size_t)(half * 32 + row) * CONVCH;
      *(float4*)&sB[row][c4]  = *(const float4*)(gsrc + DIN + c4);
      *(float4*)&sCc[row][c4] = *(const float4*)(gsrc + DIN + DS + c4);
      *(float4*)&sx[row][c4]  = *(const float4*)(gsrc + h * HD + c4);
    }
    __syncthreads();
#pragma unroll 4
    for (int tl = 0; tl < 32; ++tl) {
      int tg = half * 32 + tl;
      float da = sda[tg], dtv = sdt[tg];
      float x = sx[tl][p];
      float cf = dtv * x;
      const float4* br = (const float4*)&sB[tl][q * 16];
      const float4* cr = (const float4*)&sCc[tl][q * 16];
      float4 B0 = br[0], B1 = br[1], B2 = br[2], B3 = br[3];
      float4 C0 = cr[0], C1 = cr[1], C2 = cr[2], C3 = cr[3];
      float y0 = 0.f, y1 = 0.f, y2 = 0.f, y3 = 0.f;
      UPDA(0, B0, C0) UPDA(1, B1, C1) UPDA(2, B2, C2) UPDA(3, B3, C3)
      float y = (y0 + y1) + (y2 + y3);
      y += __shfl_xor(y, 1);
      y += __shfl_xor(y, 2);
      cum *= da;
      if (q == 0) yl[(size_t)tg * DIN] = y;
      if (t == 0) cumout[tg] = cum;
    }
  }
  float* scp = SC + ((size_t)bh * NCHUNK + chunk) * 4096 + p * 64 + q * 16;
  *(float4*)(scp + 0)  = make_float4(st[0], st[1], st[2], st[3]);
  *(float4*)(scp + 4)  = make_float4(st[4], st[5], st[6], st[7]);
  *(float4*)(scp + 8)  = make_float4(st[8], st[9], st[10], st[11]);
  *(float4*)(scp + 12) = make_float4(st[12], st[13], st[14], st[15]);
  if (t == 0) PC[bh * NCHUNK + chunk] = cum;
}

// ---------------------------------------------------------------------------
// K6: element-parallel in-place scan over chunks: SC[c] <- exclusive prefix state.
__global__ __launch_bounds__(256) void scan_passB(
    float* __restrict__ SC, const float* __restrict__ PC) {
  int bh = blockIdx.x >> 4;
  int eg = blockIdx.x & 15;
  int e = eg * 256 + threadIdx.x;
  float h = 0.f;
#pragma unroll 8
  for (int c = 0; c < NCHUNK; ++c) {
    size_t idx = ((size_t)bh * NCHUNK + c) * 4096 + e;
    float s = SC[idx];
    float pcv = PC[bh * NCHUNK + c];
    SC[idx] = h;
    h = h * pcv + s;
  }
}

// ---------------------------------------------------------------------------
// K7: pass C — LDS-broadcast staging. grid (NCHUNK*4, NH, B_), block 256.
__global__ __launch_bounds__(256) void scan_passC(
    const float* __restrict__ XBC, const float* __restrict__ SC,
    const float* __restrict__ CUM, const float* __restrict__ Dp,
    float* __restrict__ YL) {
  int chunk = blockIdx.x >> 2, tq = blockIdx.x & 3;
  int h = blockIdx.y, b = blockIdx.z;
  int t = threadIdx.x;
  int p = t >> 2, q = t & 3;
  int bh = b * NH + h;
  __shared__ float sCc[16][64];
  __shared__ float sx[16][64];
  __shared__ float scum[16];
  int t0 = tq * 16;
  size_t rowbase = ((size_t)b * L_ + (size_t)chunk * CHUNK + t0) * CONVCH;
  {
    int row = t >> 4, c4 = (t & 15) * 4;
    const float* gsrc = XBC + rowbase + (size_t)row * CONVCH;
    *(float4*)&sCc[row][c4] = *(const float4*)(gsrc + DIN + DS + c4);
    *(float4*)&sx[row][c4]  = *(const float4*)(gsrc + h * HD + c4);
    if (t < 16) scum[t] = CUM[(size_t)bh * L_ + chunk * CHUNK + t0 + t];
  }
  const float* hi = SC + ((size_t)bh * NCHUNK + chunk) * 4096 + p * 64 + q * 16;
  float hreg[16];
  {
    float4 v;
    v = *(const float4*)(hi + 0);  hreg[0] = v.x; hreg[1] = v.y; hreg[2] = v.z; hreg[3] = v.w;
    v = *(const float4*)(hi + 4);  hreg[4] = v.x; hreg[5] = v.y; hreg[6] = v.z; hreg[7] = v.w;
    v = *(const float4*)(hi + 8);  hreg[8] = v.x; hreg[9] = v.y; hreg[10] = v.z; hreg[11] = v.w;
    v = *(const float4*)(hi + 12); hreg[12] = v.x; hreg[13] = v.y; hreg[14] = v.z; hreg[15] = v.w;
  }
  float Dv = Dp[h];
  float* __restrict__ yl = YL + ((size_t)b * L_ + (size_t)chunk * CHUNK + t0) * DIN + h * HD + p;
  __syncthreads();
#pragma unroll 4
  for (int tl = 0; tl < 16; ++tl) {
    const float4* cr = (const float4*)&sCc[tl][q * 16];
    float4 C0 = cr[0], C1 = cr[1], C2 = cr[2], C3 = cr[3];
    float x = sx[tl][p];
    float cum = scum[tl];
    float y0 = 0.f, y1 = 0.f, y2 = 0.f, y3 = 0.f;
    y0 += hreg[0]*C0.x;  y1 += hreg[1]*C0.y;  y2 += hreg[2]*C0.z;  y3 += hreg[3]*C0.w;
    y0 += hreg[4]*C1.x;  y1 += hreg[5]*C1.y;  y2 += hreg[6]*C1.z;  y3 += hreg[7]*C1.w;
    y0 += hreg[8]*C2.x;  y1 += hreg[9]*C2.y;  y2 += hreg[10]*C2.z; y3 += hreg[11]*C2.w;
    y0 += hreg[12]*C3.x; y1 += hreg[13]*C3.y; y2 += hreg[14]*C3.z; y3 += hreg[15]*C3.w;
    float y = (y0 + y1) + (y2 + y3);
    y += __shfl_xor(y, 1);
    y += __shfl_xor(y, 2);
    if (q == 0) {
      size_t o = (size_t)tl * DIN;
      yl[o] = yl[o] + cum * y + x * Dv;
    }
  }
}

// ---------------------------------------------------------------------------
// gate_gemm: fused gating + RMSNorm + out_proj GEMM (split-bf16 MFMA via LDS
// fragments). grid (256), block 256; 64 pixels per block -> MBUF (pix,128).
__global__ __launch_bounds__(256) void gate_gemm(
    const float* __restrict__ YL, const float* __restrict__ ZX,
    const float* __restrict__ rmsw,
    const ushort* __restrict__ Oh, const ushort* __restrict__ Ol,
    float* __restrict__ MBUF) {
  __shared__ ushort AhL[16384];   // 32 KB
  __shared__ ushort AlL[16384];   // 32 KB
  int t = threadIdx.x;
  int lp = t & 31, pp = t >> 5;
  int pix0 = blockIdx.x * 64;
  float4 w0 = *(const float4*)(rmsw + lp * 4);
  float4 w1 = *(const float4*)(rmsw + 128 + lp * 4);
  for (int it = 0; it < 8; ++it) {
    int pl = it * 8 + pp;
    size_t pix = (size_t)pix0 + pl;
    const float* y = YL + pix * DIN;
    const float* z = ZX + pix * DPROJ;
    float4 y0 = *(const float4*)(y + lp * 4);
    float4 y1 = *(const float4*)(y + 128 + lp * 4);
    float4 z0 = *(const float4*)(z + lp * 4);
    float4 z1 = *(const float4*)(z + 128 + lp * 4);
    float g[8];
    g[0] = y0.x * siluf(z0.x); g[1] = y0.y * siluf(z0.y);
    g[2] = y0.z * siluf(z0.z); g[3] = y0.w * siluf(z0.w);
    g[4] = y1.x * siluf(z1.x); g[5] = y1.y * siluf(z1.y);
    g[6] = y1.z * siluf(z1.z); g[7] = y1.w * siluf(z1.w);
    float ss = 0.f;
#pragma unroll
    for (int j = 0; j < 8; ++j) ss += g[j] * g[j];
    ss += __shfl_xor(ss, 16);
    ss += __shfl_xor(ss, 8);
    ss += __shfl_xor(ss, 4);
    ss += __shfl_xor(ss, 2);
    ss += __shfl_xor(ss, 1);
    float rs = rsqrtf(ss * (1.f / 256.f) + 1e-5f);
    float o[8];
    o[0] = g[0] * rs * w0.x; o[1] = g[1] * rs * w0.y;
    o[2] = g[2] * rs * w0.z; o[3] = g[3] * rs * w0.w;
    o[4] = g[4] * rs * w1.x; o[5] = g[5] * rs * w1.y;
    o[6] = g[6] * rs * w1.z; o[7] = g[7] * rs * w1.w;
#pragma unroll
    for (int grp = 0; grp < 2; ++grp) {
      int d = grp * 128 + lp * 4;
      int off = ((pl >> 5) * 16 + (d >> 4)) * 512 +
                ((pl & 31) + 32 * ((d & 15) >> 3)) * 8 + (d & 7);
      ushort h0 = f2bf(o[grp*4+0]), h1 = f2bf(o[grp*4+1]);
      ushort h2 = f2bf(o[grp*4+2]), h3 = f2bf(o[grp*4+3]);
      uint2 hv, lv;
      hv.x = (unsigned)h0 | ((unsigned)h1 << 16);
      hv.y = (unsigned)h2 | ((unsigned)h3 << 16);
      lv.x = (unsigned)f2bf(o[grp*4+0] - bf2f(h0)) | ((unsigned)f2bf(o[grp*4+1] - bf2f(h1)) << 16);
      lv.y = (unsigned)f2bf(o[grp*4+2] - bf2f(h2)) | ((unsigned)f2bf(o[grp*4+3] - bf2f(h3)) << 16);
      *(uint2*)(AhL + off) = hv;
      *(uint2*)(AlL + off) = lv;
    }
  }
  __syncthreads();
  int w = t >> 6, lane = t & 63;
  int pb = w >> 1, db = w & 1;
  const bf16x8* pBh = (const bf16x8*)Oh;
  const bf16x8* pBl = (const bf16x8*)Ol;
  int rowadd = 4 * (lane >> 5);
#pragma unroll
  for (int bn = 0; bn < 2; ++bn) {
    floatx16 acc;
#pragma unroll
    for (int i = 0; i < 16; ++i) acc[i] = 0.f;
    size_t bbase = ((size_t)(bn * 2 + db) * 16) * 64 + lane;
#pragma unroll
    for (int kk = 0; kk < 16; ++kk) {
      bf16x8 ah = *(const bf16x8*)(AhL + (pb * 16 + kk) * 512 + lane * 8);
      bf16x8 al = *(const bf16x8*)(AlL + (pb * 16 + kk) * 512 + lane * 8);
      bf16x8 bh = pBh[bbase + (size_t)kk * 64];
      bf16x8 bl = pBl[bbase + (size_t)kk * 64];
      acc = __builtin_amdgcn_mfma_f32_32x32x16_bf16(ah, bh, acc, 0, 0, 0);
      acc = __builtin_amdgcn_mfma_f32_32x32x16_bf16(al, bh, acc, 0, 0, 0);
      acc = __builtin_amdgcn_mfma_f32_32x32x16_bf16(ah, bl, acc, 0, 0, 0);
    }
    int c = bn * 64 + db * 32 + (lane & 31);
#pragma unroll
    for (int r = 0; r < 16; ++r) {
      int rowm = (r & 3) + 8 * (r >> 2) + rowadd;
      int pix = pix0 + pb * 32 + rowm;
      MBUF[(size_t)pix * C_ + c] = acc[r];
    }
  }
}

// ---------------------------------------------------------------------------
// K10: transpose (b,L,128) -> (b,128,L) and add noisy -> YRES.
__global__ __launch_bounds__(256) void transpose_add(
    const float* __restrict__ M, const float* __restrict__ noisy, float* __restrict__ YRES) {
  int row = blockIdx.x, b = blockIdx.y;
  int t = threadIdx.x;
  __shared__ float tile[64 * 129];
  const float* src = M + ((size_t)(b * L_ + row * 64)) * C_;
  for (int idx = t; idx < 8192; idx += 256) {
    int px = idx >> 7, c = idx & 127;
    tile[px * 129 + c] = src[idx];
  }
  __syncthreads();
  for (int idx = t; idx < 8192; idx += 256) {
    int c = idx >> 6, px = idx & 63;
    size_t o = ((size_t)(b * C_ + c)) * L_ + row * 64 + px;
    YRES[o] = noisy[o] + tile[px * 129 + c];
  }
}

// ---------------------------------------------------------------------------
// wprep_kernel: conv weights (fw2) -> bf16 A-fragments (late alias region).
__global__ __launch_bounds__(256) void wprep_kernel(
    const float* __restrict__ w, ushort* __restrict__ Wt) {
  int co = blockIdx.x;  // 0..127
  int t = threadIdx.x;
  int cb = co >> 5;
  for (int k = t; k < 1152; k += 256) {
    int kk = k >> 4, k16 = k & 15;
    int l = (co & 31) + 32 * (k16 >> 3);
    int off = (kk * 4 + cb) * 512 + l * 8 + (k16 & 7);
    Wt[off] = f2bf(w[(size_t)co * 1152 + k]);
  }
}

// ---------------------------------------------------------------------------
// im2col v2: coalesced 16B fragment writes; each thread emits 8 taps (j=0..7)
// of one (kk, nb, l) fragment row. grid (36 kk-pairs, 64 y, 4 b), block 256.
// T = float (converts to bf16) or ushort (bf16 passthrough).
template <typename T>
__global__ __launch_bounds__(256) void im2col_kernel(
    const T* __restrict__ src, ushort* __restrict__ Bm) {
  int y = blockIdx.y, b = blockIdx.z;
  int t = threadIdx.x;
  int kk = blockIdx.x * 2 + (t >> 7);
  int r = t & 127;
  int nb = r >> 6, l = r & 63;
  int x = nb * 32 + (l & 31);
  int ki0 = (l >> 5) * 8;
  const T* sb = src + (size_t)b * C_ * L_;
  ushort vals[8];
#pragma unroll
  for (int j = 0; j < 8; ++j) {
    int k = kk * 16 + ki0 + j;
    int ci = k / 9, rr = k - ci * 9;
    int iy = rr / 3, ix = rr - iy * 3;
    int yy = y + iy - 1; yy = yy < 0 ? -yy : (yy > 63 ? 126 - yy : yy);
    int xx = x + ix - 1; xx = xx < 0 ? -xx : (xx > 63 ? 126 - xx : xx);
    T v = sb[(size_t)ci * L_ + yy * 64 + xx];
    if constexpr (sizeof(T) == 4) vals[j] = f2bf((float)v);
    else vals[j] = (ushort)v;
  }
  ushort* dst = Bm + (((size_t)(b * 64 + y)) * 72 + kk) * 1024 + nb * 512 + l * 8;
  *(int4*)dst = *(int4*)vals;
}

// ---------------------------------------------------------------------------
// conv_mfma: direct fragment loads. MODE 0: bf16 out, no residual.
// MODE 1: fp32 out = res + relu(conv). grid (2, 64, 4), block 256.
template <int MODE>
__global__ __launch_bounds__(256) void conv_mfma(
    const ushort* __restrict__ Wt, const ushort* __restrict__ Bm,
    const float* __restrict__ bias, const float* __restrict__ res,
    void* __restrict__ outv) {
  int cog = blockIdx.x, y = blockIdx.y, b = blockIdx.z;
  int t = threadIdx.x;
  int w = t >> 6, lane = t & 63;
  int cb = w >> 1, nb = w & 1;
  const bf16x8* pW = (const bf16x8*)Wt + (size_t)(cog * 2 + cb) * 64 + lane;
  const bf16x8* pB = (const bf16x8*)Bm + ((size_t)(b * 64 + y) * 72) * 128 +
                     (size_t)nb * 64 + lane;
  floatx16 acc;
#pragma unroll
  for (int i = 0; i < 16; ++i) acc[i] = 0.f;
#pragma unroll 8
  for (int kk = 0; kk < 72; ++kk) {
    bf16x8 af = pW[(size_t)kk * 256];
    bf16x8 bf = pB[(size_t)kk * 128];
    acc = __builtin_amdgcn_mfma_f32_32x32x16_bf16(af, bf, acc, 0, 0, 0);
  }
  int x0 = nb * 32 + (lane & 31);
  int rowadd = 4 * (lane >> 5);
#pragma unroll
  for (int r = 0; r < 16; ++r) {
    int rowm = (r & 3) + 8 * (r >> 2) + rowadd;
    int co = cog * 64 + cb * 32 + rowm;
    size_t o = ((size_t)(b * C_ + co)) * L_ + y * 64 + x0;
    float v = fmaxf(acc[r] + bias[co], 0.f);
    if (MODE == 0) {
      ((ushort*)outv)[o] = f2bf(v);
    } else {
      ((float*)outv)[o] = v + res[o];
    }
  }
}

// ---------------------------------------------------------------------------
extern "C" void kernel_launch(void* const* d_in, const int* in_sizes, int n_in,
                              void* d_out, int out_size, void* d_ws, size_t ws_size,
                              hipStream_t stream) {
  const float* noisy   = (const float*)d_in[0];
  const float* aux     = (const float*)d_in[1];
  const float* ln_g    = (const float*)d_in[2];
  const float* ln_b    = (const float*)d_in[3];
  const float* ipw     = (const float*)d_in[4];
  const float* cw      = (const float*)d_in[5];
  const float* cbv     = (const float*)d_in[6];
  const float* A_log   = (const float*)d_in[7];
  const float* dt_bias = (const float*)d_in[8];
  const float* Dp      = (const float*)d_in[9];
  const float* rmsw    = (const float*)d_in[10];
  const float* opw     = (const float*)d_in[11];
  const float* fw1     = (const float*)d_in[12];
  const float* fb1     = (const float*)d_in[13];
  const float* fw2     = (const float*)d_in[14];
  const float* fb2     = (const float*)d_in[15];
  float* out = (float*)d_out;
  float* ws  = (float*)d_ws;

  // Workspace layout (floats). Total = 25,428,992 floats ~= 97 MB.
  // Wt1 has its full 73,728-float extent; Woh/Wol placed after it.
  const size_t OFF_ZX  = 0;                            // 16384*644; Bm aliases at conv time
  const size_t OFF_XBC = OFF_ZX + 16384UL * 644;       // 16384*384; MBUF aliases after passC
  const size_t OFF_SCN = OFF_XBC + 16384UL * 384;      // 4,194,304: Ah/Al -> SC -> FF1(bf16)|YRES
  const size_t OFF_WT  = OFF_SCN + 4194304UL;          // 73,728 floats: Wt1 (written at start)
  const size_t OFF_WO  = OFF_WT + 73728UL;             // 32,768 floats: Woh+Wol
  const size_t OFF_CUM = OFF_WT + 131072UL;            // 65,536: CUM
  const size_t OFF_YL  = OFF_CUM + 65536UL;            // 16384*256; Bn hi+lo early / Wt2 late
  const size_t OFF_PC  = OFF_YL + 16384UL * 256;       // 1024

  float* ZX   = ws + OFF_ZX;
  float* XBC  = ws + OFF_XBC;
  float* SC   = ws + OFF_SCN;
  float* CUM  = ws + OFF_CUM;
  float* YL   = ws + OFF_YL;
  float* PC   = ws + OFF_PC;
  ushort* Ah   = (ushort*)(ws + OFF_SCN);          // ln frags (dead before SC)
  ushort* Al   = Ah + 16384UL * 128;
  ushort* Bnh  = (ushort*)(ws + OFF_YL);           // in_proj weight frags (dead before YL)
  ushort* Bnl  = Bnh + 45056UL * 2;
  ushort* Wt1 = (ushort*)(ws + OFF_WT);            // 147,456 ushorts, disjoint region
  ushort* Woh  = (ushort*)(ws + OFF_WO);           // out_proj weight frags
  ushort* Wol  = Woh + 32768UL;
  float* MBUF = ws + OFF_XBC;                      // after passC
  ushort* FF1 = (ushort*)(ws + OFF_SCN);           // bf16, after SC dead
  float* YRES = ws + OFF_SCN + 2097152UL;          // last 2M floats, after passC
  ushort* Wt2 = (ushort*)(ws + OFF_YL);            // after gate_gemm (YL dead)
  ushort* Bm  = (ushort*)(ws + OFF_ZX);            // after gate_gemm (ZX dead)

  // 1) fused weight preps (in_proj, out_proj, conv1)
  wprep_all<<<432, 256, 0, stream>>>(ipw, Bnh, Bnl, opw, Woh, Wol, fw1, Wt1);
  // 2) LN -> hi+lo bf16 A-fragments
  ln_kernel<<<dim3(64, 4), 256, 0, stream>>>(noisy, ln_g, ln_b, Ah, Al);
  // 3) in_proj GEMM (split-bf16 MFMA) -> ZX
  gemm1_mfma<<<dim3(11, 256), 256, 0, stream>>>(Ah, Al, Bnh, Bnl, ZX);
  // 4) depthwise conv1d + silu -> XBC
  conv1d_silu<<<dim3(L_ / 16, B_), 384, 0, stream>>>(ZX, cw, cbv, XBC);
  // 5) chunked scan (CHUNK=64, LDS-broadcast staging)
  scan_passA<<<dim3(NCHUNK, NH, B_), 256, 0, stream>>>(XBC, ZX, dt_bias, A_log, YL, SC, PC, CUM);
  scan_passB<<<256, 256, 0, stream>>>(SC, PC);
  scan_passC<<<dim3(NCHUNK * 4, NH, B_), 256, 0, stream>>>(XBC, SC, CUM, Dp, YL);
  // 6) fused gate + RMSNorm + out_proj GEMM -> MBUF (16384 x 128)
  gate_gemm<<<256, 256, 0, stream>>>(YL, ZX, rmsw, Woh, Wol, MBUF);
  // 7) transpose back + residual -> YRES (b,C,H,W)
  transpose_add<<<dim3(64, 4), 256, 0, stream>>>(MBUF, noisy, YRES);
  // 8) ff1 = relu(conv3x3(YRES)) via bf16 MFMA implicit GEMM (bf16 output)
  im2col_kernel<float><<<dim3(36, 64, 4), 256, 0, stream>>>(YRES, Bm);
  conv_mfma<0><<<dim3(2, 64, 4), 256, 0, stream>>>(Wt1, Bm, fb1, nullptr, FF1);
  // 9) out_y = YRES + relu(conv3x3(FF1))
  wprep_kernel<<<128, 256, 0, stream>>>(fw2, Wt2);
  im2col_kernel<ushort><<<dim3(36, 64, 4), 256, 0, stream>>>(FF1, Bm);
  conv_mfma<1><<<dim3(2, 64, 4), 256, 0, stream>>>(Wt2, Bm, fb2, YRES, out);
  // 10) aux passthrough
  hipMemcpyAsync(out + 2097152, aux, 2097152UL * sizeof(float),
                 hipMemcpyDeviceToDevice, stream);
}